// Round 1
// baseline (1062.046 us; speedup 1.0000x reference)
//
#include <hip/hip_runtime.h>
#include <stdint.h>

#define Bsz 2048
#define Tt 300
#define Dd 40
#define Hh 64
#define KT 104   // D + H

__device__ __forceinline__ float rl(float v, int l) {
    return __int_as_float(__builtin_amdgcn_readlane(__float_as_int(v), l));
}
__device__ __forceinline__ float sigm(float x) {
    return __builtin_amdgcn_rcpf(1.0f + __expf(-x));
}
__device__ __forceinline__ float tanh_f(float x) {
    return 1.0f - 2.0f * __builtin_amdgcn_rcpf(1.0f + __expf(2.0f * x));
}

// LDS weight layout (bf16): halfword index ((k>>1)*64 + u)*8 + (k&1)*4 + g
// so one lane (unit u) reads a uint4 = {k0g0,k0g1,k0g2,k0g3,k1g0,k1g1,k1g2,k1g3}
__global__ __launch_bounds__(256) void lstm_kernel(
    const float* __restrict__ X,          // [B,T,D]
    const int* __restrict__ seqlen,       // [B]
    const float* __restrict__ Wk,         // [104,256] gates i,j,f,o
    const float* __restrict__ bias,       // [256]
    float* __restrict__ hfin) {           // [B,64]
  __shared__ ushort wlds[KT * 256];       // 53248 B

  const int tid = threadIdx.x;
  for (int i = tid; i < KT * 256; i += 256) {
    int k = i >> 8, c = i & 255, g = c >> 6, u = c & 63;
    uint32_t bits = __float_as_uint(Wk[i]);
    bits += 0x7FFFu + ((bits >> 16) & 1u);   // RNE to bf16
    wlds[((k >> 1) * 64 + u) * 8 + (k & 1) * 4 + g] = (ushort)(bits >> 16);
  }
  __syncthreads();

  const int wave = tid >> 6, lane = tid & 63;
  const int s0 = blockIdx.x * 8 + wave * 2;
  const int len0 = seqlen[s0], len1 = seqlen[s0 + 1];
  const int maxlen = max(len0, len1);

  float br[4];
  #pragma unroll
  for (int g = 0; g < 4; g++) br[g] = bias[g * 64 + lane];

  const float* xb0 = X + (size_t)s0 * Tt * Dd;
  const float* xb1 = xb0 + (size_t)Tt * Dd;

  float c0 = 0.f, c1 = 0.f, h0 = 0.f, h1 = 0.f, hf0 = 0.f, hf1 = 0.f;
  float x0 = 0.f, x1 = 0.f;
  if (lane < Dd) { x0 = xb0[lane]; x1 = xb1[lane]; }

  const uint4* wp = reinterpret_cast<const uint4*>(wlds);

  for (int t = 0; t < maxlen; t++) {
    // prefetch next timestep's x while we compute this one
    float nx0 = x0, nx1 = x1;
    if (t + 1 < maxlen && lane < Dd) {
      nx0 = xb0[(t + 1) * Dd + lane];
      nx1 = xb1[(t + 1) * Dd + lane];
    }
    float a00 = br[0], a01 = br[1], a02 = br[2], a03 = br[3];
    float a10 = br[0], a11 = br[1], a12 = br[2], a13 = br[3];

    #pragma unroll 5
    for (int kp = 0; kp < 20; kp++) {       // k = 0..39 : x rows
      uint4 w = wp[kp * 64 + lane];
      float i00 = rl(x0, 2 * kp), i01 = rl(x0, 2 * kp + 1);
      float i10 = rl(x1, 2 * kp), i11 = rl(x1, 2 * kp + 1);
      float wa0 = __uint_as_float(w.x << 16), wa1 = __uint_as_float(w.x & 0xFFFF0000u);
      float wa2 = __uint_as_float(w.y << 16), wa3 = __uint_as_float(w.y & 0xFFFF0000u);
      float wb0 = __uint_as_float(w.z << 16), wb1 = __uint_as_float(w.z & 0xFFFF0000u);
      float wb2 = __uint_as_float(w.w << 16), wb3 = __uint_as_float(w.w & 0xFFFF0000u);
      a00 = fmaf(i00, wa0, fmaf(i01, wb0, a00));
      a01 = fmaf(i00, wa1, fmaf(i01, wb1, a01));
      a02 = fmaf(i00, wa2, fmaf(i01, wb2, a02));
      a03 = fmaf(i00, wa3, fmaf(i01, wb3, a03));
      a10 = fmaf(i10, wa0, fmaf(i11, wb0, a10));
      a11 = fmaf(i10, wa1, fmaf(i11, wb1, a11));
      a12 = fmaf(i10, wa2, fmaf(i11, wb2, a12));
      a13 = fmaf(i10, wa3, fmaf(i11, wb3, a13));
    }
    #pragma unroll 4
    for (int kp = 0; kp < 32; kp++) {       // k = 40..103 : h rows
      uint4 w = wp[(kp + 20) * 64 + lane];
      float i00 = rl(h0, 2 * kp), i01 = rl(h0, 2 * kp + 1);
      float i10 = rl(h1, 2 * kp), i11 = rl(h1, 2 * kp + 1);
      float wa0 = __uint_as_float(w.x << 16), wa1 = __uint_as_float(w.x & 0xFFFF0000u);
      float wa2 = __uint_as_float(w.y << 16), wa3 = __uint_as_float(w.y & 0xFFFF0000u);
      float wb0 = __uint_as_float(w.z << 16), wb1 = __uint_as_float(w.z & 0xFFFF0000u);
      float wb2 = __uint_as_float(w.w << 16), wb3 = __uint_as_float(w.w & 0xFFFF0000u);
      a00 = fmaf(i00, wa0, fmaf(i01, wb0, a00));
      a01 = fmaf(i00, wa1, fmaf(i01, wb1, a01));
      a02 = fmaf(i00, wa2, fmaf(i01, wb2, a02));
      a03 = fmaf(i00, wa3, fmaf(i01, wb3, a03));
      a10 = fmaf(i10, wa0, fmaf(i11, wb0, a10));
      a11 = fmaf(i10, wa1, fmaf(i11, wb1, a11));
      a12 = fmaf(i10, wa2, fmaf(i11, wb2, a12));
      a13 = fmaf(i10, wa3, fmaf(i11, wb3, a13));
    }
    // gate order i, j, f, o
    c0 = c0 * sigm(a02 + 1.0f) + sigm(a00) * tanh_f(a01);
    h0 = tanh_f(c0) * sigm(a03);
    c1 = c1 * sigm(a12 + 1.0f) + sigm(a10) * tanh_f(a11);
    h1 = tanh_f(c1) * sigm(a13);
    hf0 = (t == len0 - 1) ? h0 : hf0;
    hf1 = (t == len1 - 1) ? h1 : hf1;
    x0 = nx0; x1 = nx1;
  }
  hfin[s0 * 64 + lane] = hf0;
  hfin[(s0 + 1) * 64 + lane] = hf1;
}

// one block per sample: dense1+BN -> LDS -> 4 logits/thread -> softmax
__global__ __launch_bounds__(128) void head_kernel(
    const float* __restrict__ hfin,
    const float* __restrict__ W1, const float* __restrict__ b1,
    const float* __restrict__ gamma, const float* __restrict__ beta,
    const float* __restrict__ mmean, const float* __restrict__ mvar,
    const float* __restrict__ W2, const float* __restrict__ b2,
    float* __restrict__ out) {
  __shared__ float hl[64];
  __shared__ float d1[128];
  __shared__ float redm[2], reds[2];
  const int b = blockIdx.x, tid = threadIdx.x;
  if (tid < 64) hl[tid] = hfin[b * 64 + tid];
  __syncthreads();
  float acc = b1[tid];
  #pragma unroll 8
  for (int k = 0; k < 64; k++) acc = fmaf(hl[k], W1[k * 128 + tid], acc);
  acc = fmaxf(acc, 0.f);
  acc = gamma[tid] * (acc - mmean[tid]) * rsqrtf(mvar[tid] + 1e-3f) + beta[tid];
  d1[tid] = acc;
  __syncthreads();
  const float4* b2v = reinterpret_cast<const float4*>(b2);
  float4 l = b2v[tid];
  #pragma unroll 4
  for (int k = 0; k < 128; k++) {
    float dk = d1[k];
    float4 w = *reinterpret_cast<const float4*>(&W2[k * 512 + tid * 4]);
    l.x = fmaf(dk, w.x, l.x);
    l.y = fmaf(dk, w.y, l.y);
    l.z = fmaf(dk, w.z, l.z);
    l.w = fmaf(dk, w.w, l.w);
  }
  float m = fmaxf(fmaxf(l.x, l.y), fmaxf(l.z, l.w));
  #pragma unroll
  for (int off = 1; off < 64; off <<= 1) m = fmaxf(m, __shfl_xor(m, off));
  if ((tid & 63) == 0) redm[tid >> 6] = m;
  __syncthreads();
  m = fmaxf(redm[0], redm[1]);
  float e0 = __expf(l.x - m), e1 = __expf(l.y - m);
  float e2 = __expf(l.z - m), e3 = __expf(l.w - m);
  float s = (e0 + e1) + (e2 + e3);
  #pragma unroll
  for (int off = 1; off < 64; off <<= 1) s += __shfl_xor(s, off);
  if ((tid & 63) == 0) reds[tid >> 6] = s;
  __syncthreads();
  s = reds[0] + reds[1];
  float inv = __builtin_amdgcn_rcpf(s);
  float4 o = make_float4(e0 * inv, e1 * inv, e2 * inv, e3 * inv);
  *reinterpret_cast<float4*>(&out[(size_t)b * 512 + tid * 4]) = o;
}

extern "C" void kernel_launch(void* const* d_in, const int* in_sizes, int n_in,
                              void* d_out, int out_size, void* d_ws, size_t ws_size,
                              hipStream_t stream) {
  const float* X      = (const float*)d_in[0];
  const int*   seqlen = (const int*)d_in[1];
  const float* Wk     = (const float*)d_in[2];
  const float* bias   = (const float*)d_in[3];
  const float* W1     = (const float*)d_in[4];
  const float* b1     = (const float*)d_in[5];
  const float* gam    = (const float*)d_in[6];
  const float* bet    = (const float*)d_in[7];
  const float* mmean  = (const float*)d_in[8];
  const float* mvar   = (const float*)d_in[9];
  const float* W2     = (const float*)d_in[10];
  const float* b2     = (const float*)d_in[11];
  float* out  = (float*)d_out;
  float* hfin = (float*)d_ws;   // 2048*64 floats = 512 KB scratch

  lstm_kernel<<<dim3(256), dim3(256), 0, stream>>>(X, seqlen, Wk, bias, hfin);
  head_kernel<<<dim3(2048), dim3(128), 0, stream>>>(hfin, W1, b1, gam, bet,
                                                    mmean, mvar, W2, b2, out);
}

// Round 2
// 427.455 us; speedup vs baseline: 2.4846x; 2.4846x over previous
//
#include <hip/hip_runtime.h>
#include <stdint.h>

#define TT 300
#define DD 40
#define SB 8          // samples per block
#define AROW 200      // A row stride in halfwords (100 words -> bank stride 4 -> 2-way = free)
#define ZROW 260      // zbuf row stride in words (16B-aligned rows)

typedef __attribute__((ext_vector_type(8))) short short8;
typedef __attribute__((ext_vector_type(4))) float f32x4;

__device__ __forceinline__ ushort f2bf(float f) {
  uint32_t b = __float_as_uint(f);
  b += 0x7FFFu + ((b >> 16) & 1u);   // RNE
  return (ushort)(b >> 16);
}
__device__ __forceinline__ float sigm(float x) {
  return __builtin_amdgcn_rcpf(1.0f + __expf(-x));
}
__device__ __forceinline__ float tanh_f(float x) {
  return 1.0f - 2.0f * __builtin_amdgcn_rcpf(1.0f + __expf(2.0f * x));
}

// K layout (192 = 6 ktiles of 32):
//   k   0..39  : x_t           (W rows 0..39)
//   k  40..63  : zero pad
//   k  64..127 : h_hi (bf16)   (W rows 40..103)
//   k 128..191 : h_lo (bf16 residual) -> reuses h weight frags (ksrc = k-64)
// Weight columns permuted: col = u*4 + g  (u=unit 0..63, g=gate i,j,f,o)
// so wave w (cols 64w..64w+63) owns units 16w..16w+15 with all 4 gates.
__global__ __launch_bounds__(256, 1) void lstm_mfma_kernel(
    const float* __restrict__ X, const int* __restrict__ seqlen,
    const float* __restrict__ Wk, const float* __restrict__ bias,
    float* __restrict__ hfin)
{
  __shared__ ushort wstage[64 * 128];   // 16 KB, init-only staging (one wave's cols)
  __shared__ ushort Ash[16 * AROW];     // 6.4 KB, A matrix (bf16), rows 8..15 stay 0
  __shared__ float zbuf[8 * ZROW];      // 8.3 KB, pre-activation z (fp32)

  const int tid = threadIdx.x;
  const int wv = tid >> 6, lane = tid & 63;
  const int s0 = blockIdx.x * SB;

  for (int i = tid; i < 16 * AROW; i += 256) Ash[i] = 0;

  // ---- load B fragments into registers (24 frags = 96 VGPRs/wave) ----
  // B[k][n] fragment layout: n = lane&15, k = ktile*32 + (lane>>4)*8 + j
  short8 Bf[6][4];
  for (int c = 0; c < 4; ++c) {
    __syncthreads();
    for (int i = tid; i < 64 * 128; i += 256) {   // stage cols 64c..64c+63, transposed
      int kp = i >> 6, cc = i & 63;
      ushort v = 0;
      int ks = (kp < 40) ? kp : ((kp >= 64) ? (kp - 24) : -1);
      if (ks >= 0) {
        int u = c * 16 + (cc >> 2), g = cc & 3;
        v = f2bf(Wk[ks * 256 + g * 64 + u]);
      }
      wstage[cc * 128 + kp] = v;
    }
    __syncthreads();   // also drains wave c-1's frag reads (lgkmcnt(0) before s_barrier)
    if (wv == c) {
      #pragma unroll
      for (int kt = 0; kt < 6; ++kt) {
        int kk = ((kt < 4) ? kt * 32 : (kt * 32 - 64)) + (lane >> 4) * 8;
        #pragma unroll
        for (int nt = 0; nt < 4; ++nt) {
          int cc = nt * 16 + (lane & 15);
          Bf[kt][nt] = *reinterpret_cast<const short8*>(&wstage[cc * 128 + kk]);
        }
      }
    }
  }

  // ---- per-thread activation assignment: pairs (s=ps, u0) and (ps, u1) ----
  const int ps = tid >> 5;
  const int u0 = (2 * tid) & 63, u1 = u0 + 1;
  const int mylen = seqlen[s0 + ps];
  const float bi0 = bias[u0],      bj0 = bias[64 + u0];
  const float bfg0 = bias[128 + u0] + 1.0f, bo0 = bias[192 + u0];
  const float bi1 = bias[u1],      bj1 = bias[64 + u1];
  const float bfg1 = bias[128 + u1] + 1.0f, bo1 = bias[192 + u1];

  int ml = seqlen[s0 + (lane & 7)];
  #pragma unroll
  for (int off = 1; off < 64; off <<= 1) ml = max(ml, __shfl_xor(ml, off));

  // x prefetch: 320 values/step; thread covers i=tid and (tid<64) i=tid+256
  const int iA = tid, iB = 256 + tid;
  const int sA = (iA * 205) >> 13, dA = iA - sA * 40;
  int sB = (iB * 205) >> 13; if (sB > 7) sB = 7;
  const int dB = iB - sB * 40;
  const float* xpA = X + (size_t)(s0 + sA) * (TT * DD) + dA;
  const float* xpB = X + (size_t)(s0 + sB) * (TT * DD) + dB;
  const bool hasB = (iB < SB * DD);

  Ash[sA * AROW + dA] = f2bf(xpA[0]);          // x_0
  if (hasB) Ash[sB * AROW + dB] = f2bf(xpB[0]);
  __syncthreads();

  float c0 = 0.f, c1 = 0.f, hf0 = 0.f, hf1 = 0.f;

  for (int t = 0; t < ml; ++t) {
    // A fragments: A[m=lane&15][k = kt*32 + (lane>>4)*8 + j]
    short8 Af[6];
    #pragma unroll
    for (int kt = 0; kt < 6; ++kt)
      Af[kt] = *reinterpret_cast<const short8*>(
          &Ash[(lane & 15) * AROW + kt * 32 + (lane >> 4) * 8]);

    const bool pre = (t + 1 < ml);
    float xnA = 0.f, xnB = 0.f;
    if (pre) {
      xnA = xpA[(t + 1) * DD];
      if (hasB) xnB = xpB[(t + 1) * DD];
    }

    f32x4 zero4 = {0.f, 0.f, 0.f, 0.f};
    f32x4 acc[4] = {zero4, zero4, zero4, zero4};
    #pragma unroll
    for (int kt = 0; kt < 6; ++kt) {
      #pragma unroll
      for (int nt = 0; nt < 4; ++nt)
        acc[nt] = __builtin_amdgcn_mfma_f32_16x16x32_bf16(Af[kt], Bf[kt][nt], acc[nt], 0, 0, 0);
    }

    // C/D layout: col = lane&15, row = (lane>>4)*4 + reg; rows 0..7 are real samples
    if (lane < 32) {
      const int q = lane >> 4, cl = lane & 15;
      #pragma unroll
      for (int nt = 0; nt < 4; ++nt) {
        #pragma unroll
        for (int r = 0; r < 4; ++r)
          zbuf[(q * 4 + r) * ZROW + wv * 64 + nt * 16 + cl] = acc[nt][r];
      }
    }
    __syncthreads();

    // gate quad (i,j,f,o) for (ps,u) is contiguous at permuted cols u*4..u*4+3
    f32x4 z0 = *reinterpret_cast<const f32x4*>(&zbuf[ps * ZROW + u0 * 4]);
    f32x4 z1 = *reinterpret_cast<const f32x4*>(&zbuf[ps * ZROW + u1 * 4]);
    float nc0 = c0 * sigm(z0[2] + bfg0) + sigm(z0[0] + bi0) * tanh_f(z0[1] + bj0);
    float nh0 = tanh_f(nc0) * sigm(z0[3] + bo0);
    float nc1 = c1 * sigm(z1[2] + bfg1) + sigm(z1[0] + bi1) * tanh_f(z1[1] + bj1);
    float nh1 = tanh_f(nc1) * sigm(z1[3] + bo1);
    c0 = nc0; c1 = nc1;
    if (t == mylen - 1) { hf0 = nh0; hf1 = nh1; }

    // h feedback as bf16 hi+lo (effective ~fp32 precision)
    ushort hh0 = f2bf(nh0);
    ushort hl0 = f2bf(nh0 - __uint_as_float((uint32_t)hh0 << 16));
    ushort hh1 = f2bf(nh1);
    ushort hl1 = f2bf(nh1 - __uint_as_float((uint32_t)hh1 << 16));
    Ash[ps * AROW + 64 + u0] = hh0;
    Ash[ps * AROW + 128 + u0] = hl0;
    Ash[ps * AROW + 64 + u1] = hh1;
    Ash[ps * AROW + 128 + u1] = hl1;
    if (pre) {
      Ash[sA * AROW + dA] = f2bf(xnA);
      if (hasB) Ash[sB * AROW + dB] = f2bf(xnB);
    }
    __syncthreads();
  }

  hfin[(size_t)(s0 + ps) * 64 + u0] = hf0;
  hfin[(size_t)(s0 + ps) * 64 + u1] = hf1;
}

// head: 16 samples per block (128 blocks) -> W2 read 128x instead of 2048x
__global__ __launch_bounds__(256, 1) void head_kernel(
    const float* __restrict__ hfin,
    const float* __restrict__ W1, const float* __restrict__ b1,
    const float* __restrict__ gamma, const float* __restrict__ beta,
    const float* __restrict__ mmean, const float* __restrict__ mvar,
    const float* __restrict__ W2, const float* __restrict__ b2,
    float* __restrict__ out)
{
  __shared__ float hl[16 * 64];     // 4 KB
  __shared__ float d1t[128 * 20];   // transposed d1 [k][s], stride 20 (16B-aligned)
  __shared__ float lg[16 * 516];    // 33 KB logits
  const int tid = threadIdx.x;
  const int b0 = blockIdx.x * 16;

  for (int i = tid; i < 16 * 64; i += 256) hl[i] = hfin[(size_t)b0 * 64 + i];
  __syncthreads();

  { // dense1 + BN + ReLU: thread = (col j, sample-group sg), 8 samples each
    const int j = tid & 127, sg = tid >> 7;
    float acc[8];
    const float bb = b1[j];
    #pragma unroll
    for (int s = 0; s < 8; ++s) acc[s] = bb;
    for (int k = 0; k < 64; ++k) {
      float w = W1[k * 128 + j];
      #pragma unroll
      for (int s = 0; s < 8; ++s) acc[s] = fmaf(hl[(sg * 8 + s) * 64 + k], w, acc[s]);
    }
    const float ga = gamma[j], be = beta[j], mm = mmean[j];
    const float iv = rsqrtf(mvar[j] + 1e-3f);
    #pragma unroll
    for (int s = 0; s < 8; ++s) {
      float v = fmaxf(acc[s], 0.f);
      d1t[j * 20 + sg * 8 + s] = ga * (v - mm) * iv + be;
    }
  }
  __syncthreads();

  { // logits: thread owns cols 2*tid, 2*tid+1 for all 16 samples
    const int cA = tid * 2;
    float accA[16], accB[16];
    const float bA = b2[cA], bB = b2[cA + 1];
    #pragma unroll
    for (int s = 0; s < 16; ++s) { accA[s] = bA; accB[s] = bB; }
    for (int k = 0; k < 128; ++k) {
      const float2 w = *reinterpret_cast<const float2*>(&W2[k * 512 + cA]);
      const f32x4 dq0 = *reinterpret_cast<const f32x4*>(&d1t[k * 20]);
      const f32x4 dq1 = *reinterpret_cast<const f32x4*>(&d1t[k * 20 + 4]);
      const f32x4 dq2 = *reinterpret_cast<const f32x4*>(&d1t[k * 20 + 8]);
      const f32x4 dq3 = *reinterpret_cast<const f32x4*>(&d1t[k * 20 + 12]);
      #pragma unroll
      for (int s = 0; s < 4; ++s) {
        accA[s]      = fmaf(dq0[s], w.x, accA[s]);      accB[s]      = fmaf(dq0[s], w.y, accB[s]);
        accA[s + 4]  = fmaf(dq1[s], w.x, accA[s + 4]);  accB[s + 4]  = fmaf(dq1[s], w.y, accB[s + 4]);
        accA[s + 8]  = fmaf(dq2[s], w.x, accA[s + 8]);  accB[s + 8]  = fmaf(dq2[s], w.y, accB[s + 8]);
        accA[s + 12] = fmaf(dq3[s], w.x, accA[s + 12]); accB[s + 12] = fmaf(dq3[s], w.y, accB[s + 12]);
      }
    }
    #pragma unroll
    for (int s = 0; s < 16; ++s) {
      lg[s * 516 + cA]     = accA[s];
      lg[s * 516 + cA + 1] = accB[s];
    }
  }
  __syncthreads();

  { // softmax: wave handles 4 samples, 8 cols/lane
    const int w = tid >> 6, lane = tid & 63;
    #pragma unroll
    for (int si = 0; si < 4; ++si) {
      const int s = w * 4 + si;
      float v[8];
      float m = -3.4e38f;
      #pragma unroll
      for (int i = 0; i < 8; ++i) { v[i] = lg[s * 516 + lane + 64 * i]; m = fmaxf(m, v[i]); }
      #pragma unroll
      for (int off = 1; off < 64; off <<= 1) m = fmaxf(m, __shfl_xor(m, off));
      float sum = 0.f;
      #pragma unroll
      for (int i = 0; i < 8; ++i) { v[i] = __expf(v[i] - m); sum += v[i]; }
      #pragma unroll
      for (int off = 1; off < 64; off <<= 1) sum += __shfl_xor(sum, off);
      const float inv = __builtin_amdgcn_rcpf(sum);
      #pragma unroll
      for (int i = 0; i < 8; ++i)
        out[(size_t)(b0 + s) * 512 + lane + 64 * i] = v[i] * inv;
    }
  }
}

extern "C" void kernel_launch(void* const* d_in, const int* in_sizes, int n_in,
                              void* d_out, int out_size, void* d_ws, size_t ws_size,
                              hipStream_t stream) {
  const float* X      = (const float*)d_in[0];
  const int*   seqlen = (const int*)d_in[1];
  const float* Wk     = (const float*)d_in[2];
  const float* bias   = (const float*)d_in[3];
  const float* W1     = (const float*)d_in[4];
  const float* b1     = (const float*)d_in[5];
  const float* gam    = (const float*)d_in[6];
  const float* bet    = (const float*)d_in[7];
  const float* mmean  = (const float*)d_in[8];
  const float* mvar   = (const float*)d_in[9];
  const float* W2     = (const float*)d_in[10];
  const float* b2     = (const float*)d_in[11];
  float* out  = (float*)d_out;
  float* hfin = (float*)d_ws;   // 2048*64 fp32 = 512 KB

  lstm_mfma_kernel<<<dim3(256), dim3(256), 0, stream>>>(X, seqlen, Wk, bias, hfin);
  head_kernel<<<dim3(128), dim3(256), 0, stream>>>(hfin, W1, b1, gam, bet,
                                                   mmean, mvar, W2, b2, out);
}